// Round 9
// baseline (117.653 us; speedup 1.0000x reference)
//
#include <hip/hip_runtime.h>

// SpectralPooling via split-bf16 MFMA.  [r9 = r6 source, attribution probe:
// k1 launched 3x (idempotent) to expose per-kernel time via dur_us delta]
// y = A x_D A x_H A x_W x, A = 48x64 composed (truncate32 + iDCT48) matrix.
// All stages use v_mfma_f32_16x16x32_bf16 (M,N=16, K=32).
// Layouts (m89-verified): A-op row=lane&15, k=8*(lane>>4)+j.
// B-op col=lane&15, k=8*(lane>>4)+j. D: col=lane&15, row=4*(lane>>4)+reg.

typedef __attribute__((ext_vector_type(8))) short short8;
typedef __attribute__((ext_vector_type(4))) float f32x4;
typedef __attribute__((ext_vector_type(4))) unsigned int u32x4;
typedef __attribute__((ext_vector_type(2))) unsigned int u32x2;

static __device__ __forceinline__ unsigned short f2bf(float f) {
    unsigned int u = __float_as_uint(f);
    u += 0x7fffu + ((u >> 16) & 1u);          // RNE
    return (unsigned short)(u >> 16);
}
static __device__ __forceinline__ float bf2f(unsigned short h) {
    return __uint_as_float(((unsigned int)h) << 16);
}

// Table: tbl[s][ks][t][lane][j], s=hi/lo split, ks=k-step(32), t=16-col tile.
// Element = split_s( At[k][a] ), k = 8*(lane>>4)+j+32*ks, a = 16*t+(lane&15).
// Same lane layout serves both A-op and B-op roles.
static __device__ __forceinline__ short8 ldtbl(const unsigned short* __restrict__ tbl,
                                               int s, int ks, int t, int l) {
    return *(const short8*)(tbl + (unsigned)((((s * 2 + ks) * 3 + t) * 64 + l) * 8));
}

__global__ __launch_bounds__(256) void gen_tbl(unsigned short* __restrict__ tbl) {
    int i = blockIdx.x * 256 + threadIdx.x;     // 0..3071
    int j = i & 7;
    int lane = (i >> 3) & 63;
    int tks = i >> 9;                           // ks*3 + t
    int t = tks % 3, ks = tks / 3;
    int k = 8 * (lane >> 4) + j + 32 * ks;      // 0..63
    int a = 16 * t + (lane & 15);               // 0..47
    const float PI = 3.14159265358979323846f;
    const float s48 = 0.20412414523193150818f;  // sqrt(2/48)
    const float s64 = 0.17677669529663688110f;  // sqrt(2/64)
    float s = 0.f;
    for (int kk = 0; kk < 32; ++kk) {
        int m48 = ((2 * a + 1) * kk) % 192;     // exact angle reduction mod 4N
        int m64 = ((2 * k + 1) * kk) % 256;
        float c48 = cosf(PI * (float)m48 / 96.0f) * s48;
        float c64 = cosf(PI * (float)m64 / 128.0f) * s64;
        if (kk == 0) { c48 *= 0.70710678118654752440f; c64 *= 0.70710678118654752440f; }
        s += c48 * c64;
    }
    unsigned short hi = f2bf(s);
    unsigned short lo = f2bf(s - bf2f(hi));
    tbl[i] = hi;            // s=0 slab
    tbl[i + 3072] = lo;     // s=1 slab
}

// ---------------- K1: per (bc,d) slice: W then H, both on MFMA ----------------
#define SC_S 72   // u16 row stride for sC: rows 144 B (16B-aligned); b128 reads
                  // land 8 lanes/bank-quad = LDS BW floor, b64 writes 2-way (free)
__global__ __launch_bounds__(256) void k1_wh(const float* __restrict__ x,
                                             const unsigned short* __restrict__ tbl,
                                             unsigned short* __restrict__ y2) {
    __shared__ unsigned short sC[48 * SC_S];   // C1^T [a2][h], single bf16, 6.9 KB

    const int tid = threadIdx.x;
    const int blk = blockIdx.x;                         // bc*64 + d
    const int g = __builtin_amdgcn_readfirstlane(tid >> 6);
    const int l = tid & 63;
    const int r = l & 15;
    const int kq = l >> 4;

    // ---- stage W: C1[h][a2] = sum_w x[h][w] * At[w][a2]; wave g owns h rows [16g,16g+16)
    f32x4 z = {0.f, 0.f, 0.f, 0.f};
    f32x4 acc0 = z, acc1 = z, acc2 = z;
    const float* xb = x + (unsigned)(blk * 4096 + (16 * g + r) * 64 + kq * 8);
    #pragma unroll
    for (int ks = 0; ks < 2; ++ks) {
        float4 xa = *(const float4*)(xb + 32 * ks);
        float4 xc = *(const float4*)(xb + 32 * ks + 4);
        float v[8] = {xa.x, xa.y, xa.z, xa.w, xc.x, xc.y, xc.z, xc.w};
        short8 xh, xl;
        #pragma unroll
        for (int j = 0; j < 8; ++j) {
            // truncation split: hi = chop(f), lo = chop(f - hi)
            unsigned int u = __float_as_uint(v[j]);
            float rem = v[j] - __uint_as_float(u & 0xffff0000u);
            xh[j] = (short)(u >> 16);
            xl[j] = (short)(__float_as_uint(rem) >> 16);
        }
        #pragma unroll
        for (int t = 0; t < 3; ++t) {
            short8 wh = ldtbl(tbl, 0, ks, t, l);
            f32x4 a = (t == 0) ? acc0 : (t == 1) ? acc1 : acc2;
            a = __builtin_amdgcn_mfma_f32_16x16x32_bf16(xh, wh, a, 0, 0, 0);
            a = __builtin_amdgcn_mfma_f32_16x16x32_bf16(xl, wh, a, 0, 0, 0);
            if (t == 0) acc0 = a; else if (t == 1) acc1 = a; else acc2 = a;
        }
    }
    // store C1^T single-bf16 to LDS: lane holds C1[h=16g+4kq+rr][a2=16t+r]
    #pragma unroll
    for (int t = 0; t < 3; ++t) {
        f32x4 a = (t == 0) ? acc0 : (t == 1) ? acc1 : acc2;
        u32x2 pk;
        pk[0] = (unsigned int)f2bf(a[0]) | ((unsigned int)f2bf(a[1]) << 16);
        pk[1] = (unsigned int)f2bf(a[2]) | ((unsigned int)f2bf(a[3]) << 16);
        *(u32x2*)&sC[(16 * t + r) * SC_S + 16 * g + 4 * kq] = pk;   // 4 consecutive h
    }
    __syncthreads();

    // ---- stage H (swapped operands): C2[a2][a1] = sum_h C1[h][a2] * At[h][a1]
    // A-op = C1 frag (row=a2, k=h) = ONE contiguous ds_read_b128.
    // B-op = tbl (col=a1, k=h).
    // D: row(4kq+rr)=a2-local -> 4 consecutive a2 per lane => 8B stores.
    auto loadA = [&](int m, int ks) -> short8 {
        return *(const short8*)&sC[(16 * m + r) * SC_S + 8 * kq + 32 * ks];
    };
    auto storeY = [&](int m, int n, f32x4 c) {
        // a2 = 16m + 4kq + rr (consecutive), a1 = 16n + r
        u32x2 pk;
        pk[0] = (unsigned int)f2bf(c[0]) | ((unsigned int)f2bf(c[1]) << 16);
        pk[1] = (unsigned int)f2bf(c[2]) | ((unsigned int)f2bf(c[3]) << 16);
        *(u32x2*)(y2 + (unsigned)(blk * 2304 + (16 * n + r) * 48 + 16 * m + 4 * kq)) = pk;
    };

    if (g < 3) {
        // wave g: column n=g (a1-tile), rows m=0,1 (a2-tiles)
        f32x4 c0 = z, c1 = z;
        #pragma unroll
        for (int ks = 0; ks < 2; ++ks) {
            short8 ah = ldtbl(tbl, 0, ks, g, l);
            c0 = __builtin_amdgcn_mfma_f32_16x16x32_bf16(loadA(0, ks), ah, c0, 0, 0, 0);
            c1 = __builtin_amdgcn_mfma_f32_16x16x32_bf16(loadA(1, ks), ah, c1, 0, 0, 0);
        }
        storeY(0, g, c0);
        storeY(1, g, c1);
    } else {
        // wave 3: row m=2 (a2-tile), all columns n=0..2 (A-frag shared across n)
        f32x4 t0 = z, t1 = z, t2 = z;
        #pragma unroll
        for (int ks = 0; ks < 2; ++ks) {
            short8 ca = loadA(2, ks);
            t0 = __builtin_amdgcn_mfma_f32_16x16x32_bf16(ca, ldtbl(tbl, 0, ks, 0, l), t0, 0, 0, 0);
            t1 = __builtin_amdgcn_mfma_f32_16x16x32_bf16(ca, ldtbl(tbl, 0, ks, 1, l), t1, 0, 0, 0);
            t2 = __builtin_amdgcn_mfma_f32_16x16x32_bf16(ca, ldtbl(tbl, 0, ks, 2, l), t2, 0, 0, 0);
        }
        storeY(2, 0, t0);
        storeY(2, 1, t1);
        storeY(2, 2, t2);
    }
}

// ---------------- K2: D-transform, LDS-staged, swapped operands ----------------
// out[bc][a0][a1][a2] = sum_d y2[bc][d][a1][a2] * At[d][a0]
// A-op = y2 fragment (row=a2-in-tile, k=d), B-op = tbl (col=a0-in-tile, k=d).
__global__ __launch_bounds__(256) void k2_d(const unsigned short* __restrict__ y2,
                                            const unsigned short* __restrict__ tbl,
                                            float* __restrict__ out) {
    __shared__ unsigned short sY[4 * 3 * 64 * 16];   // [a1l][m][d][c] = 24 KB

    const int tid = threadIdx.x;
    const int blk = blockIdx.x;            // bc*12 + quad
    const int bc = blk / 12;
    const int quad = blk % 12;

    // ---- stage: y2 tile (all d, 4 a1, all a2) -> LDS, coalesced 16B loads
    const unsigned short* yb = y2 + (unsigned)(bc * 64 * 2304 + quad * 4 * 48);
    #pragma unroll
    for (int jj = 0; jj < 6; ++jj) {
        int f = tid + 256 * jj;            // 0..1535 (16B chunks)
        int d = f / 24;                    // 24 chunks per d
        int p = f % 24;
        int a1l = p / 6;                   // 6 chunks per a1-row (48 u16)
        int q = p % 6;
        int a2 = q * 8;
        int m = a2 >> 4;
        int c0 = a2 & 15;
        u32x4 v = *(const u32x4*)(yb + (unsigned)(d * 2304 + a1l * 48 + a2));
        *(u32x4*)&sY[(((a1l * 3 + m) * 64) + d) * 16 + c0] = v;
    }
    __syncthreads();

    const int g = __builtin_amdgcn_readfirstlane(tid >> 6);   // wave -> a1 local
    const int l = tid & 63;
    const int r = l & 15;
    const int kq = l >> 4;
    const int a1 = quad * 4 + g;

    // hoist B-frags (constant table, L1-hot)
    short8 th[2][3], tl[2][3];
    #pragma unroll
    for (int ks = 0; ks < 2; ++ks)
        #pragma unroll
        for (int n = 0; n < 3; ++n) {
            th[ks][n] = ldtbl(tbl, 0, ks, n, l);
            tl[ks][n] = ldtbl(tbl, 1, ks, n, l);
        }

    f32x4 z = {0.f, 0.f, 0.f, 0.f};
    f32x4 acc[3][3];
    #pragma unroll
    for (int m = 0; m < 3; ++m)
        #pragma unroll
        for (int n = 0; n < 3; ++n) acc[m][n] = z;

    #pragma unroll
    for (int m = 0; m < 3; ++m) {
        #pragma unroll
        for (int ks = 0; ks < 2; ++ks) {
            short8 ya;     // A-frag: row=a2=16m+r, k=d=8kq+j+32ks
            #pragma unroll
            for (int j = 0; j < 8; ++j)
                ya[j] = (short)sY[((g * 3 + m) * 64 + 8 * kq + 32 * ks + j) * 16 + r];
            #pragma unroll
            for (int n = 0; n < 3; ++n) {
                acc[m][n] = __builtin_amdgcn_mfma_f32_16x16x32_bf16(ya, th[ks][n], acc[m][n], 0, 0, 0);
                acc[m][n] = __builtin_amdgcn_mfma_f32_16x16x32_bf16(ya, tl[ks][n], acc[m][n], 0, 0, 0);
            }
        }
    }

    // ---- store: lane (kq,r), tile (m,n): out[a0=16n+r][a1][a2=16m+4kq+rr]
    #pragma unroll
    for (int m = 0; m < 3; ++m)
        #pragma unroll
        for (int n = 0; n < 3; ++n) {
            float4 v;
            v.x = acc[m][n][0]; v.y = acc[m][n][1]; v.z = acc[m][n][2]; v.w = acc[m][n][3];
            float* dst = out + ((size_t)(bc * 48 + 16 * n + r) * 48 + a1) * 48 + 16 * m + 4 * kq;
            *(float4*)dst = v;
        }
}

extern "C" void kernel_launch(void* const* d_in, const int* in_sizes, int n_in,
                              void* d_out, int out_size, void* d_ws, size_t ws_size,
                              hipStream_t stream) {
    const float* x = (const float*)d_in[0];
    float* out = (float*)d_out;

    unsigned short* tbl = (unsigned short*)d_ws;                     // 12 KiB
    unsigned short* y2 = (unsigned short*)((char*)d_ws + 65536);     // 36.75 MiB bf16

    gen_tbl<<<12, 256, 0, stream>>>(tbl);
    // ATTRIBUTION PROBE: k1 launched 3x (idempotent -> identical y2 every time).
    // k1_us = (dur_r9 - dur_r6) / 2.
    k1_wh<<<128 * 64, 256, 0, stream>>>(x, tbl, y2);
    k1_wh<<<128 * 64, 256, 0, stream>>>(x, tbl, y2);
    k1_wh<<<128 * 64, 256, 0, stream>>>(x, tbl, y2);
    k2_d<<<128 * 12, 256, 0, stream>>>(y2, tbl, out);
}

// Round 10
// 52.800 us; speedup vs baseline: 2.2282x; 2.2282x over previous
//
#include <hip/hip_runtime.h>

// SpectralPooling via split-bf16 MFMA.
// y = A x_D A x_H A x_W x, A = 48x64 composed (truncate32 + iDCT48) matrix.
// All stages v_mfma_f32_16x16x32_bf16. Layouts (m89): A-op row=lane&15,
// k=8*(lane>>4)+j. B-op col=lane&15, same k. D: col=lane&15, row=4*(lane>>4)+reg.
// r10: matrix table computed at COMPILE TIME (constexpr, 6 separate 512-entry
// evaluations to stay under clang's constexpr-step limit) -> no gen kernel.
// k2: matrix-lo dropped (18 MFMA); staging rewritten: d-pair scattered global
// reads + conflict-free u32 LDS writes + XOR-swizzled [c][d] layout so the
// k=d A-fragment is ONE ds_read_b128 (replaces 48 scalar 8-way-conflicted reads).

typedef __attribute__((ext_vector_type(8))) short short8;
typedef __attribute__((ext_vector_type(8))) unsigned short u16x8;
typedef __attribute__((ext_vector_type(4))) float f32x4;
typedef __attribute__((ext_vector_type(4))) unsigned int u32x4;
typedef __attribute__((ext_vector_type(2))) unsigned int u32x2;

// ======================= compile-time matrix table =======================
constexpr double CPI   = 3.14159265358979323846264338327950288;
constexpr double CS48  = 0.20412414523193150818310700622549;   // sqrt(2/48)
constexpr double CS64  = 0.17677669529663688110021109052621;   // sqrt(2/64)
constexpr double CISQ2 = 0.70710678118654752440084436210485;   // 1/sqrt(2)

constexpr double ccos_raw(double x) {            // |x| <= pi/2, Taylor
    double x2 = x * x, term = 1.0, s = 1.0;
    for (int n = 1; n <= 13; ++n) { term *= -x2 / double((2 * n - 1) * (2 * n)); s += term; }
    return s;
}
constexpr double ccos(double x) {                // 0 <= x < 2*pi
    if (x > CPI) x = 2.0 * CPI - x;
    double sgn = 1.0;
    if (x > CPI * 0.5) { x = CPI - x; sgn = -1.0; }
    return sgn * ccos_raw(x);
}
constexpr unsigned short f2bf_c(float f) {       // RNE float->bf16 bits
    if (f == 0.0f) return 0;
    int sign = 0; double x = f;
    if (x < 0) { sign = 1; x = -x; }
    int e = 0;
    while (x >= 2.0) { x *= 0.5; ++e; }
    while (x < 1.0)  { x *= 2.0; --e; }
    double v = x * 128.0;
    long iv = (long)v; double fr = v - (double)iv;
    long m = iv;
    if (fr > 0.5 || (fr == 0.5 && (iv & 1))) ++m;
    if (m == 256) { m = 128; ++e; }
    return (unsigned short)((sign << 15) | ((e + 127) << 7) | (int)(m - 128));
}

struct CosTab48 { double v[192];
    constexpr CosTab48() : v{} { for (int m = 0; m < 192; ++m) v[m] = ccos(CPI * m / 96.0) * CS48; } };
struct CosTab64 { double v[256];
    constexpr CosTab64() : v{} { for (int m = 0; m < 256; ++m) v[m] = ccos(CPI * m / 128.0) * CS64; } };
constexpr CosTab48 CT48{};
constexpr CosTab64 CT64{};

// Part p = (ks*3 + t): 512 bf16 entries: idx = l*8+j, k = 8*(l>>4)+j+32*ks,
// a = 16*t+(l&15); value = hi-bf16 of sum_{kk<32} c48[a,kk]*c64[k,kk].
struct Part512 { unsigned short hi[512];
    constexpr Part512(int p) : hi{} {
        int ks = p / 3, t = p % 3;
        for (int i = 0; i < 512; ++i) {
            int j = i & 7, l = i >> 3;
            int k = 8 * (l >> 4) + j + 32 * ks;
            int a = 16 * t + (l & 15);
            double s = 0.0;
            for (int kk = 0; kk < 32; ++kk) {
                int m48 = ((2 * a + 1) * kk) % 192;
                int m64 = ((2 * k + 1) * kk) % 256;
                double c48 = CT48.v[m48], c64 = CT64.v[m64];
                if (kk == 0) { c48 *= CISQ2; c64 *= CISQ2; }
                s += c48 * c64;
            }
            hi[i] = f2bf_c((float)s);
        }
    }
};
constexpr Part512 TP0(0), TP1(1), TP2(2), TP3(3), TP4(4), TP5(5);

struct AllTbl { alignas(16) unsigned short v[6][512];
    constexpr AllTbl() : v{} {
        for (int i = 0; i < 512; ++i) v[0][i] = TP0.hi[i];
        for (int i = 0; i < 512; ++i) v[1][i] = TP1.hi[i];
        for (int i = 0; i < 512; ++i) v[2][i] = TP2.hi[i];
        for (int i = 0; i < 512; ++i) v[3][i] = TP3.hi[i];
        for (int i = 0; i < 512; ++i) v[4][i] = TP4.hi[i];
        for (int i = 0; i < 512; ++i) v[5][i] = TP5.hi[i];
    }
};
__device__ constexpr AllTbl g_tbl{};

static __device__ __forceinline__ short8 ldtbl(int ks, int t, int l) {
    return *(const short8*)&g_tbl.v[ks * 3 + t][l * 8];
}

static __device__ __forceinline__ unsigned short f2bf(float f) {
    unsigned int u = __float_as_uint(f);
    u += 0x7fffu + ((u >> 16) & 1u);          // RNE
    return (unsigned short)(u >> 16);
}

// ---------------- K1: per (bc,d) slice: W then H, both on MFMA ----------------
// [UNCHANGED from r6 except table source — measured at its 28 us traffic floor]
#define SC_S 72   // u16 row stride: 144 B rows (16B-aligned), b128 reads clean
__global__ __launch_bounds__(256) void k1_wh(const float* __restrict__ x,
                                             unsigned short* __restrict__ y2) {
    __shared__ unsigned short sC[48 * SC_S];   // C1^T [a2][h], single bf16, 6.9 KB

    const int tid = threadIdx.x;
    const int blk = blockIdx.x;                         // bc*64 + d
    const int g = __builtin_amdgcn_readfirstlane(tid >> 6);
    const int l = tid & 63;
    const int r = l & 15;
    const int kq = l >> 4;

    // ---- stage W: C1[h][a2] = sum_w x[h][w] * At[w][a2]; wave g owns h rows [16g,16g+16)
    f32x4 z = {0.f, 0.f, 0.f, 0.f};
    f32x4 acc0 = z, acc1 = z, acc2 = z;
    const float* xb = x + (unsigned)(blk * 4096 + (16 * g + r) * 64 + kq * 8);
    #pragma unroll
    for (int ks = 0; ks < 2; ++ks) {
        float4 xa = *(const float4*)(xb + 32 * ks);
        float4 xc = *(const float4*)(xb + 32 * ks + 4);
        float v[8] = {xa.x, xa.y, xa.z, xa.w, xc.x, xc.y, xc.z, xc.w};
        short8 xh, xl;
        #pragma unroll
        for (int j = 0; j < 8; ++j) {
            // truncation split: hi = chop(f), lo = chop(f - hi)
            unsigned int u = __float_as_uint(v[j]);
            float rem = v[j] - __uint_as_float(u & 0xffff0000u);
            xh[j] = (short)(u >> 16);
            xl[j] = (short)(__float_as_uint(rem) >> 16);
        }
        #pragma unroll
        for (int t = 0; t < 3; ++t) {
            short8 wh = ldtbl(ks, t, l);
            f32x4 a = (t == 0) ? acc0 : (t == 1) ? acc1 : acc2;
            a = __builtin_amdgcn_mfma_f32_16x16x32_bf16(xh, wh, a, 0, 0, 0);
            a = __builtin_amdgcn_mfma_f32_16x16x32_bf16(xl, wh, a, 0, 0, 0);
            if (t == 0) acc0 = a; else if (t == 1) acc1 = a; else acc2 = a;
        }
    }
    // store C1^T single-bf16 to LDS: lane holds C1[h=16g+4kq+rr][a2=16t+r]
    #pragma unroll
    for (int t = 0; t < 3; ++t) {
        f32x4 a = (t == 0) ? acc0 : (t == 1) ? acc1 : acc2;
        u32x2 pk;
        pk[0] = (unsigned int)f2bf(a[0]) | ((unsigned int)f2bf(a[1]) << 16);
        pk[1] = (unsigned int)f2bf(a[2]) | ((unsigned int)f2bf(a[3]) << 16);
        *(u32x2*)&sC[(16 * t + r) * SC_S + 16 * g + 4 * kq] = pk;   // 4 consecutive h
    }
    __syncthreads();

    // ---- stage H (swapped operands): C2[a2][a1] = sum_h C1[h][a2] * At[h][a1]
    auto loadA = [&](int m, int ks) -> short8 {
        return *(const short8*)&sC[(16 * m + r) * SC_S + 8 * kq + 32 * ks];
    };
    auto storeY = [&](int m, int n, f32x4 c) {
        // a2 = 16m + 4kq + rr (consecutive), a1 = 16n + r
        u32x2 pk;
        pk[0] = (unsigned int)f2bf(c[0]) | ((unsigned int)f2bf(c[1]) << 16);
        pk[1] = (unsigned int)f2bf(c[2]) | ((unsigned int)f2bf(c[3]) << 16);
        *(u32x2*)(y2 + (unsigned)(blk * 2304 + (16 * n + r) * 48 + 16 * m + 4 * kq)) = pk;
    };

    if (g < 3) {
        f32x4 c0 = z, c1 = z;
        #pragma unroll
        for (int ks = 0; ks < 2; ++ks) {
            short8 ah = ldtbl(ks, g, l);
            c0 = __builtin_amdgcn_mfma_f32_16x16x32_bf16(loadA(0, ks), ah, c0, 0, 0, 0);
            c1 = __builtin_amdgcn_mfma_f32_16x16x32_bf16(loadA(1, ks), ah, c1, 0, 0, 0);
        }
        storeY(0, g, c0);
        storeY(1, g, c1);
    } else {
        f32x4 t0 = z, t1 = z, t2 = z;
        #pragma unroll
        for (int ks = 0; ks < 2; ++ks) {
            short8 ca = loadA(2, ks);
            t0 = __builtin_amdgcn_mfma_f32_16x16x32_bf16(ca, ldtbl(ks, 0, l), t0, 0, 0, 0);
            t1 = __builtin_amdgcn_mfma_f32_16x16x32_bf16(ca, ldtbl(ks, 1, l), t1, 0, 0, 0);
            t2 = __builtin_amdgcn_mfma_f32_16x16x32_bf16(ca, ldtbl(ks, 2, l), t2, 0, 0, 0);
        }
        storeY(2, 0, t0);
        storeY(2, 1, t1);
        storeY(2, 2, t2);
    }
}

// ---------------- K2: D-transform, swizzled-transpose staging ----------------
// out[bc][a0][a1][a2] = sum_d y2[bc][d][a1][a2] * At[d][a0]
// LDS layout sY[a1l][m][c=16][dstore=64] u16, dstore = d ^ ((c&7)<<3).
// Stage: thread owns d-pair d0=2*dh; writes u32 (d0,d0+1 packed) at
// bank = dh^(e<<2) -> 2-way (free). Read: A-frag (row=a2=16m+r, k=d=8kq+32ks+j)
// = ONE b128 at swizzled offset (8-way = 1KB/instr floor).
__global__ __launch_bounds__(256) void k2_d(const unsigned short* __restrict__ y2,
                                            float* __restrict__ out) {
    __shared__ unsigned short sY[4 * 3 * 16 * 64];   // 24 KB

    const int tid = threadIdx.x;
    const int blk = blockIdx.x;            // bc*12 + quad
    const int bc = blk / 12;
    const int quad = blk % 12;

    const unsigned short* yb = y2 + (unsigned)(bc * 147456 + quad * 4 * 48);
    unsigned int* S32 = (unsigned int*)sY;
    const int dh = tid & 31;               // d-pair index, d0 = 2*dh
    #pragma unroll
    for (int jj = 0; jj < 3; ++jj) {
        int cp = (tid >> 5) + 8 * jj;      // 0..23
        int a1l = cp & 3, q = cp >> 2;     // q 0..5
        int m = q >> 1, c0 = 8 * (q & 1);
        u16x8 v0 = *(const u16x8*)(yb + (unsigned)((2 * dh) * 2304 + a1l * 48 + q * 8));
        u16x8 v1 = *(const u16x8*)(yb + (unsigned)((2 * dh + 1) * 2304 + a1l * 48 + q * 8));
        unsigned int base = (unsigned)(((a1l * 3 + m) * 16 + c0) * 32);
        #pragma unroll
        for (int e = 0; e < 8; ++e)
            S32[base + e * 32 + (dh ^ (e << 2))] =
                (unsigned int)v0[e] | ((unsigned int)v1[e] << 16);
    }
    __syncthreads();

    const int g = __builtin_amdgcn_readfirstlane(tid >> 6);   // wave -> a1 local
    const int l = tid & 63;
    const int r = l & 15;
    const int kq = l >> 4;
    const int a1 = quad * 4 + g;

    // hoist B-frags (constant table)
    short8 th[2][3];
    #pragma unroll
    for (int ks = 0; ks < 2; ++ks)
        #pragma unroll
        for (int n = 0; n < 3; ++n) th[ks][n] = ldtbl(ks, n, l);

    f32x4 z = {0.f, 0.f, 0.f, 0.f};
    f32x4 acc[3][3];
    #pragma unroll
    for (int m = 0; m < 3; ++m)
        #pragma unroll
        for (int n = 0; n < 3; ++n) acc[m][n] = z;

    #pragma unroll
    for (int m = 0; m < 3; ++m) {
        #pragma unroll
        for (int ks = 0; ks < 2; ++ks) {
            // A-frag: row=a2=16m+r, k=d=8kq+32ks+j -> one swizzled b128
            short8 ya = *(const short8*)&sY[(unsigned)(((g * 3 + m) * 16 + r) * 64
                                            + ((8 * kq + 32 * ks) ^ ((r & 7) << 3)))];
            #pragma unroll
            for (int n = 0; n < 3; ++n)
                acc[m][n] = __builtin_amdgcn_mfma_f32_16x16x32_bf16(ya, th[ks][n], acc[m][n], 0, 0, 0);
        }
    }

    // ---- store: lane (kq,r), tile (m,n): out[a0=16n+r][a1][a2=16m+4kq+rr]
    #pragma unroll
    for (int m = 0; m < 3; ++m)
        #pragma unroll
        for (int n = 0; n < 3; ++n) {
            float4 v;
            v.x = acc[m][n][0]; v.y = acc[m][n][1]; v.z = acc[m][n][2]; v.w = acc[m][n][3];
            float* dst = out + ((size_t)(bc * 48 + 16 * n + r) * 48 + a1) * 48 + 16 * m + 4 * kq;
            *(float4*)dst = v;
        }
}

extern "C" void kernel_launch(void* const* d_in, const int* in_sizes, int n_in,
                              void* d_out, int out_size, void* d_ws, size_t ws_size,
                              hipStream_t stream) {
    const float* x = (const float*)d_in[0];
    float* out = (float*)d_out;

    unsigned short* y2 = (unsigned short*)d_ws;     // 36.75 MiB bf16

    k1_wh<<<128 * 64, 256, 0, stream>>>(x, y2);
    k2_d<<<128 * 12, 256, 0, stream>>>(y2, out);
}